// Round 2
// baseline (19515.446 us; speedup 1.0000x reference)
//
#include <hip/hip_runtime.h>
#include <math.h>
#include <stdio.h>
#include <stdint.h>

#define NH 256
#define NH3 768
#define FNODE 133
#define FEDGE 7
#define LDW_GATE1 263   // H + F_EDGE
#define NGRAPH 4096
#define NTASK 12
#define SLOPE 0.01f
#define ENC_NEG_INF 0x007FFFFFu
#define CHUNK 7168

static __device__ __forceinline__ float lrelu_f(float x) { return x > 0.f ? x : SLOPE * x; }

static __device__ __forceinline__ unsigned fenc(float x) {
    unsigned u = __float_as_uint(x);
    return (u & 0x80000000u) ? ~u : (u | 0x80000000u);
}
static __device__ __forceinline__ float fdec(unsigned u) {
    u = (u & 0x80000000u) ? (u & 0x7FFFFFFFu) : ~u;
    return __uint_as_float(u);
}

// C[M,Nout] = act(A[M,K] @ W[Nout,:K(ldW)]^T + bias) ; act: 0 none, 1 lrelu, 2 elu
__global__ __launch_bounds__(256) void gemm_nt(
    const float* __restrict__ A, const float* __restrict__ W,
    const float* __restrict__ bias, float* __restrict__ C,
    int M, int K, int Nout, int ldW, int act)
{
    __shared__ float As[16][65];
    __shared__ float Ws[16][65];
    const int bm = blockIdx.y * 64;
    const int bn = blockIdx.x * 64;
    const int tid = threadIdx.x;
    const int tr = tid >> 4, tc = tid & 15;
    const int lrow = tid >> 2, lk = (tid & 3) * 4;
    float acc[4][4] = {};
    for (int k0 = 0; k0 < K; k0 += 16) {
#pragma unroll
        for (int j = 0; j < 4; ++j) {
            int gk = k0 + lk + j;
            int ga = bm + lrow;
            As[lk + j][lrow] = (ga < M && gk < K) ? A[(size_t)ga * K + gk] : 0.f;
            int gw = bn + lrow;
            Ws[lk + j][lrow] = (gw < Nout && gk < K) ? W[(size_t)gw * ldW + gk] : 0.f;
        }
        __syncthreads();
#pragma unroll
        for (int kk = 0; kk < 16; ++kk) {
            float av[4], bv[4];
#pragma unroll
            for (int i = 0; i < 4; ++i) av[i] = As[kk][tr * 4 + i];
#pragma unroll
            for (int i = 0; i < 4; ++i) bv[i] = Ws[kk][tc * 4 + i];
#pragma unroll
            for (int i = 0; i < 4; ++i)
#pragma unroll
                for (int j = 0; j < 4; ++j) acc[i][j] += av[i] * bv[j];
        }
        __syncthreads();
    }
#pragma unroll
    for (int i = 0; i < 4; ++i) {
        int m = bm + tr * 4 + i;
        if (m >= M) continue;
#pragma unroll
        for (int j = 0; j < 4; ++j) {
            int n = bn + tc * 4 + j;
            if (n >= Nout) continue;
            float v = acc[i][j];
            if (bias) v += bias[n];
            if (act == 1) v = lrelu_f(v);
            else if (act == 2) v = (v > 0.f ? v : expm1f(v));
            C[(size_t)m * Nout + n] = v;
        }
    }
}

__global__ void fill_f32(float* p, float v, size_t n) {
    size_t i = (size_t)blockIdx.x * 256 + threadIdx.x;
    if (i < n) p[i] = v;
}
__global__ void fill_u32(unsigned* p, unsigned v, size_t n) {
    size_t i = (size_t)blockIdx.x * 256 + threadIdx.x;
    if (i < n) p[i] = v;
}
__global__ void relu_inplace(float* p, size_t n) {
    size_t i = (size_t)blockIdx.x * 256 + threadIdx.x;
    if (i < n) p[i] = fmaxf(p[i], 0.f);
}

// o1[n] = X[n,:]·v1 ; o2[n] = X[n,:]·v2 (optional)
__global__ __launch_bounds__(256) void node_dot(
    const float* __restrict__ X, const float* __restrict__ v1, const float* __restrict__ v2,
    float* __restrict__ o1, float* __restrict__ o2, int M)
{
    __shared__ float s1[NH], s2[NH];
    int tid = threadIdx.x;
    s1[tid] = v1[tid];
    s2[tid] = v2 ? v2[tid] : 0.f;
    __syncthreads();
    int wv = tid >> 6, lane = tid & 63;
    for (int n = blockIdx.x * 4 + wv; n < M; n += gridDim.x * 4) {
        float a1 = 0.f, a2 = 0.f;
#pragma unroll
        for (int i = 0; i < 4; ++i) {
            int hh = i * 64 + lane;
            float xv = X[(size_t)n * NH + hh];
            a1 += xv * s1[hh];
            a2 += xv * s2[hh];
        }
#pragma unroll
        for (int off = 32; off; off >>= 1) { a1 += __shfl_xor(a1, off); a2 += __shfl_xor(a2, off); }
        if (lane == 0) { o1[n] = a1; if (o2) o2[n] = a2; }
    }
}

// per-edge GATEConv logit: lrelu( dot(lrelu(nodepart[src] + edge_attr@W1b^T), att_l) + dotr[dst] )
__global__ __launch_bounds__(256) void gate_edge_logit(
    const float* __restrict__ nodepart, const float* __restrict__ edge_attr,
    const float* __restrict__ gate_lin1_w, const float* __restrict__ att_l,
    const float* __restrict__ dotr, const int* __restrict__ src, const int* __restrict__ dst,
    float* __restrict__ logit, int E)
{
    __shared__ float sW[NH * FEDGE];
    __shared__ float sAl[NH];
    int tid = threadIdx.x;
    for (int i = tid; i < NH * FEDGE; i += 256)
        sW[i] = gate_lin1_w[(size_t)(i / FEDGE) * LDW_GATE1 + NH + (i % FEDGE)];
    sAl[tid] = att_l[tid];
    __syncthreads();
    int wv = tid >> 6, lane = tid & 63;
    for (int e = blockIdx.x * 4 + wv; e < E; e += gridDim.x * 4) {
        int s = src[e], d = dst[e];
        float ea[FEDGE];
#pragma unroll
        for (int f = 0; f < FEDGE; ++f) ea[f] = edge_attr[(size_t)e * FEDGE + f];
        float acc = 0.f;
#pragma unroll
        for (int i = 0; i < 4; ++i) {
            int hh = i * 64 + lane;
            float v = nodepart[(size_t)s * NH + hh];
#pragma unroll
            for (int f = 0; f < FEDGE; ++f) v += ea[f] * sW[hh * FEDGE + f];
            v = lrelu_f(v);
            acc += v * sAl[hh];
        }
#pragma unroll
        for (int off = 32; off; off >>= 1) acc += __shfl_xor(acc, off);
        if (lane == 0) logit[e] = lrelu_f(acc + dotr[d]);
    }
}

__global__ void atom_edge_logit(
    const float* __restrict__ asrc, const float* __restrict__ adst,
    const int* __restrict__ src, const int* __restrict__ dst, float* __restrict__ logit, int E)
{
    int i = blockIdx.x * 256 + threadIdx.x;
    if (i < E) logit[i] = lrelu_f(asrc[src[i]] + adst[dst[i]]);
}

__global__ void seg_max_k(const float* __restrict__ logit, const int* __restrict__ seg,
                          unsigned* __restrict__ menc, int n)
{
    int i = blockIdx.x * 256 + threadIdx.x;
    if (i < n) atomicMax(&menc[seg[i]], fenc(logit[i]));
}
__global__ void seg_exp_k(const float* __restrict__ logit, const int* __restrict__ seg,
                          const unsigned* __restrict__ menc, float* __restrict__ ex,
                          float* __restrict__ ssum, int n)
{
    int i = blockIdx.x * 256 + threadIdx.x;
    if (i < n) {
        float m = fdec(menc[seg[i]]);
        float e = expf(logit[i] - m);
        ex[i] = e;
        atomicAdd(&ssum[seg[i]], e);
    }
}

// hraw[dst] += V[src] * (ex[e]/(ssum[dst]+1e-16)) ; wave per edge
__global__ __launch_bounds__(256) void scatter_msg(
    const float* __restrict__ V, const float* __restrict__ ex, const float* __restrict__ ssum,
    const int* __restrict__ src, const int* __restrict__ dst, float* __restrict__ hout, int E)
{
    int wv = threadIdx.x >> 6, lane = threadIdx.x & 63;
    for (int e = blockIdx.x * 4 + wv; e < E; e += gridDim.x * 4) {
        int s = src[e], d = dst[e];
        float alpha = ex[e] / (ssum[d] + 1e-16f);
#pragma unroll
        for (int i = 0; i < 4; ++i) {
            int hh = i * 64 + lane;
            atomicAdd(&hout[(size_t)d * NH + hh], V[(size_t)s * NH + hh] * alpha);
        }
    }
}

// out[seg[n]] += X[n]  (wave per node)
__global__ __launch_bounds__(256) void scatter_rows(
    const float* __restrict__ X, const int* __restrict__ seg, float* __restrict__ out, int M)
{
    int wv = threadIdx.x >> 6, lane = threadIdx.x & 63;
    for (int n = blockIdx.x * 4 + wv; n < M; n += gridDim.x * 4) {
        int b = seg[n];
#pragma unroll
        for (int i = 0; i < 4; ++i) {
            int hh = i * 64 + lane;
            atomicAdd(&out[(size_t)b * NH + hh], X[(size_t)n * NH + hh]);
        }
    }
}

// out[seg[n]] += X[n] * (ex[n]/(ssum[seg[n]]+1e-16))
__global__ __launch_bounds__(256) void scatter_rows_alpha(
    const float* __restrict__ X, const float* __restrict__ ex, const float* __restrict__ ssum,
    const int* __restrict__ seg, float* __restrict__ out, int M)
{
    int wv = threadIdx.x >> 6, lane = threadIdx.x & 63;
    for (int n = blockIdx.x * 4 + wv; n < M; n += gridDim.x * 4) {
        int b = seg[n];
        float alpha = ex[n] / (ssum[b] + 1e-16f);
#pragma unroll
        for (int i = 0; i < 4; ++i) {
            int hh = i * 64 + lane;
            atomicAdd(&out[(size_t)b * NH + hh], X[(size_t)n * NH + hh] * alpha);
        }
    }
}

__global__ void mol_node_logit(
    const float* __restrict__ asrc, const float* __restrict__ dstdot,
    const int* __restrict__ batch, float* __restrict__ logit, int n)
{
    int i = blockIdx.x * 256 + threadIdx.x;
    if (i < n) logit[i] = lrelu_f(asrc[i] + dstdot[batch[i]]);
}

// v[j] = sum_i a[i] * Wm[i*NH + j] = (W^T a)[j]  (one block, 256 threads)
__global__ __launch_bounds__(256) void matvec_left(
    const float* __restrict__ Wm, const float* __restrict__ a, float* __restrict__ v)
{
    int j = threadIdx.x;
    float s = 0.f;
    for (int i = 0; i < NH; ++i) s += a[i] * Wm[(size_t)i * NH + j];
    v[j] = s;
}

// GRU elementwise combine (gate order r,z,n) followed by ReLU
__global__ __launch_bounds__(256) void gru_combine(
    const float* __restrict__ gi, const float* __restrict__ gh,
    const float* __restrict__ b_ih, const float* __restrict__ b_hh,
    const float* __restrict__ hprev, float* __restrict__ out, int M)
{
    size_t idx = (size_t)blockIdx.x * 256 + threadIdx.x;
    if (idx >= (size_t)M * NH) return;
    int n = (int)(idx >> 8), j = (int)(idx & (NH - 1));
    size_t b3 = (size_t)n * NH3;
    float ir = gi[b3 + j] + b_ih[j];
    float iz = gi[b3 + NH + j] + b_ih[NH + j];
    float inn = gi[b3 + 2 * NH + j] + b_ih[2 * NH + j];
    float hr = gh[b3 + j] + b_hh[j];
    float hz = gh[b3 + NH + j] + b_hh[NH + j];
    float hn = gh[b3 + 2 * NH + j] + b_hh[2 * NH + j];
    float r = 1.f / (1.f + expf(-(ir + hr)));
    float z = 1.f / (1.f + expf(-(iz + hz)));
    float nn = tanhf(inn + r * hn);
    float hv = (1.f - z) * nn + z * hprev[idx];
    out[idx] = fmaxf(hv, 0.f);
}

extern "C" void kernel_launch(void* const* d_in, const int* in_sizes, int n_in,
                              void* d_out, int out_size, void* d_ws, size_t ws_size,
                              hipStream_t stream)
{
    const float* x          = (const float*)d_in[0];
    const float* edge_attr  = (const float*)d_in[1];
    const float* lin1_w     = (const float*)d_in[2];
    const float* lin1_b     = (const float*)d_in[3];
    const float* gate_att_l = (const float*)d_in[4];
    const float* gate_att_r = (const float*)d_in[5];
    const float* gate_lin1_w= (const float*)d_in[6];
    const float* gate_lin2_w= (const float*)d_in[7];
    const float* gate_bias  = (const float*)d_in[8];
    const float* atom_lin_w = (const float*)d_in[9];
    const float* atom_att_src=(const float*)d_in[10];
    const float* atom_att_dst=(const float*)d_in[11];
    const float* atom_bias  = (const float*)d_in[12];
    const float* gru_w_ih   = (const float*)d_in[13];
    const float* gru_w_hh   = (const float*)d_in[14];
    const float* gru_b_ih   = (const float*)d_in[15];
    const float* gru_b_hh   = (const float*)d_in[16];
    const float* mol_lin_w  = (const float*)d_in[17];
    const float* mol_att_src= (const float*)d_in[18];
    const float* mol_att_dst= (const float*)d_in[19];
    const float* mol_bias   = (const float*)d_in[20];
    const float* mol_gru_w_ih=(const float*)d_in[21];
    const float* mol_gru_w_hh=(const float*)d_in[22];
    const float* mol_gru_b_ih=(const float*)d_in[23];
    const float* mol_gru_b_hh=(const float*)d_in[24];
    const float* lin2_w     = (const float*)d_in[25];
    const float* lin2_b     = (const float*)d_in[26];
    const float* fc_w       = (const float*)d_in[27];
    const float* fc_b       = (const float*)d_in[28];
    const int*   edge_index = (const int*)d_in[29];
    const int*   batch      = (const int*)d_in[30];

    const int N = in_sizes[0] / FNODE;
    const int E = in_sizes[1] / FEDGE;
    const int G = NGRAPH;
    const int* src = edge_index;
    const int* dst = edge_index + E;

    float* w = (float*)d_ws;
    size_t o = 0;
    auto alloc = [&](size_t cnt) { size_t r = o; o += cnt; return r; };
    const size_t o_B1   = alloc((size_t)N * NH);          // x0 -> xcur (in-place GRU)
    const size_t o_B2   = alloc((size_t)N * NH);          // nodepart -> hraw ; mol-phase buffers
    const size_t o_B3   = alloc((size_t)CHUNK * 1792);    // tmp(256) + gi(768) + gh(768) per chunk row
    const size_t o_elog = alloc((size_t)E);
    const size_t o_eexp = alloc((size_t)E);
    const size_t o_dotr = alloc((size_t)N);
    const size_t o_adst = alloc((size_t)N);
    const size_t o_smax = alloc((size_t)N);               // unsigned
    const size_t o_ssum = alloc((size_t)N);
    const size_t o_nlog = alloc((size_t)N);
    const size_t o_nexp = alloc((size_t)N);
    const size_t o_vvec = alloc((size_t)NH);
    const size_t o_usrc = alloc((size_t)NH);
    const size_t o_udst = alloc((size_t)NH);
    const size_t o_ddot = alloc((size_t)G);
    if (o * sizeof(float) > ws_size) {
        fprintf(stderr, "kernel_launch: ws too small: need %zu have %zu\n", o * 4, ws_size);
        return;
    }

    float* B1   = w + o_B1;
    float* B2   = w + o_B2;
    float* B3   = w + o_B3;
    float* elog = w + o_elog;
    float* eexp = w + o_eexp;
    float* dotr = w + o_dotr;
    float* adst = w + o_adst;
    unsigned* smax = (unsigned*)(w + o_smax);
    float* ssum = w + o_ssum;
    float* nlog = w + o_nlog;
    float* nexp = w + o_nexp;
    float* vvec = w + o_vvec;
    float* usrc = w + o_usrc;
    float* udst = w + o_udst;
    float* ddot = w + o_ddot;

    // mol-phase sub-buffers inside B2 (node-phase hraw is dead by then)
    float* gout   = B2;                       // G*NH
    float* hraw_g = B2 + (size_t)G * NH;      // G*NH
    float* h_g    = B2 + (size_t)2 * G * NH;  // G*NH
    float* gig    = B2 + (size_t)3 * G * NH;  // G*NH3
    float* ghg    = B2 + (size_t)3 * G * NH + (size_t)G * NH3; // G*NH3
    float* emb    = B2 + (size_t)3 * G * NH + (size_t)2 * G * NH3; // G*NH

    const int BLK = 256;
    auto cdiv = [](size_t a, size_t b) { return (int)((a + b - 1) / b); };
    dim3 gridNH(cdiv(NH, 64), cdiv(N, 64));
    const int gridEdgeWave = cdiv(E, 4);
    const int gridNodeWave = cdiv(N, 4);
    const int gridEdgeThr = cdiv(E, BLK);
    const int gridNodeThr = cdiv(N, BLK);
    const size_t NHtot = (size_t)N * NH;

    // Per-layer tail: h = elu(hraw@Wh^T + bh); GRU(h, xbuf) -> xbuf (in place, chunked)
    auto run_tail = [&](const float* Wh, const float* bh,
                        const float* wih, const float* whh,
                        const float* bih, const float* bhh, float* xbuf) {
        float* tmp = B3;
        float* gi  = B3 + (size_t)CHUNK * NH;
        float* gh  = B3 + (size_t)CHUNK * NH + (size_t)CHUNK * NH3;
        for (int c0 = 0; c0 < N; c0 += CHUNK) {
            int mc = (N - c0) < CHUNK ? (N - c0) : CHUNK;
            dim3 gH(cdiv(NH, 64), cdiv(mc, 64));
            dim3 g3(cdiv(NH3, 64), cdiv(mc, 64));
            gemm_nt<<<gH, BLK, 0, stream>>>(B2 + (size_t)c0 * NH, Wh, bh, tmp, mc, NH, NH, NH, 2);
            gemm_nt<<<g3, BLK, 0, stream>>>(tmp, wih, nullptr, gi, mc, NH, NH3, NH, 0);
            gemm_nt<<<g3, BLK, 0, stream>>>(xbuf + (size_t)c0 * NH, whh, nullptr, gh, mc, NH, NH3, NH, 0);
            gru_combine<<<cdiv((size_t)mc * NH, BLK), BLK, 0, stream>>>(
                gi, gh, bih, bhh, xbuf + (size_t)c0 * NH, xbuf + (size_t)c0 * NH, mc);
        }
    };

    // ---------- x0 = lrelu(x @ lin1_w^T + lin1_b) ----------
    gemm_nt<<<gridNH, BLK, 0, stream>>>(x, lin1_w, lin1_b, B1, N, FNODE, NH, FNODE, 1);

    // ---------- GATEConv ----------
    // nodepart = x0 @ W1a^T  (W1a = gate_lin1_w[:, :256], row stride 263)
    gemm_nt<<<gridNH, BLK, 0, stream>>>(B1, gate_lin1_w, nullptr, B2, N, NH, NH, LDW_GATE1, 0);
    node_dot<<<gridNodeWave, BLK, 0, stream>>>(B1, gate_att_r, nullptr, dotr, nullptr, N);
    gate_edge_logit<<<gridEdgeWave, BLK, 0, stream>>>(B2, edge_attr, gate_lin1_w, gate_att_l,
                                                      dotr, src, dst, elog, E);
    fill_u32<<<gridNodeThr, BLK, 0, stream>>>(smax, ENC_NEG_INF, N);
    fill_f32<<<gridNodeThr, BLK, 0, stream>>>(ssum, 0.f, N);
    seg_max_k<<<gridEdgeThr, BLK, 0, stream>>>(elog, dst, smax, E);
    seg_exp_k<<<gridEdgeThr, BLK, 0, stream>>>(elog, dst, smax, eexp, ssum, E);
    // hraw[dst] += x0[src]*alpha  (B2 reused; nodepart dead after logits)
    fill_f32<<<cdiv(NHtot, BLK), BLK, 0, stream>>>(B2, 0.f, NHtot);
    scatter_msg<<<gridEdgeWave, BLK, 0, stream>>>(B1, eexp, ssum, src, dst, B2, E);
    run_tail(gate_lin2_w, gate_bias, gru_w_ih, gru_w_hh, gru_b_ih, gru_b_hh, B1);

    // ---------- 3 GATConv layers ----------
    for (int l = 0; l < 3; ++l) {
        const float* wl = atom_lin_w + (size_t)l * NH * NH;
        matvec_left<<<1, BLK, 0, stream>>>(wl, atom_att_src + l * NH, usrc);
        matvec_left<<<1, BLK, 0, stream>>>(wl, atom_att_dst + l * NH, udst);
        node_dot<<<gridNodeWave, BLK, 0, stream>>>(B1, usrc, udst, dotr, adst, N);
        atom_edge_logit<<<gridEdgeThr, BLK, 0, stream>>>(dotr, adst, src, dst, elog, E);
        fill_u32<<<gridNodeThr, BLK, 0, stream>>>(smax, ENC_NEG_INF, N);
        fill_f32<<<gridNodeThr, BLK, 0, stream>>>(ssum, 0.f, N);
        seg_max_k<<<gridEdgeThr, BLK, 0, stream>>>(elog, dst, smax, E);
        seg_exp_k<<<gridEdgeThr, BLK, 0, stream>>>(elog, dst, smax, eexp, ssum, E);
        fill_f32<<<cdiv(NHtot, BLK), BLK, 0, stream>>>(B2, 0.f, NHtot);
        scatter_msg<<<gridEdgeWave, BLK, 0, stream>>>(B1, eexp, ssum, src, dst, B2, E);
        run_tail(wl, atom_bias + l * NH,
                 gru_w_ih + (size_t)(l + 1) * NH3 * NH, gru_w_hh + (size_t)(l + 1) * NH3 * NH,
                 gru_b_ih + (size_t)(l + 1) * NH3, gru_b_hh + (size_t)(l + 1) * NH3, B1);
    }

    // ---------- Molecule pooling ----------
    const size_t GHtot = (size_t)G * NH;
    fill_f32<<<cdiv(GHtot, BLK), BLK, 0, stream>>>(gout, 0.f, GHtot);
    scatter_rows<<<gridNodeWave, BLK, 0, stream>>>(B1, batch, gout, N);
    relu_inplace<<<cdiv(GHtot, BLK), BLK, 0, stream>>>(gout, GHtot);
    // a_src[n] = xcur[n]·(mol_lin_w^T mol_att_src) ; vvec = mol_lin_w^T mol_att_dst
    matvec_left<<<1, BLK, 0, stream>>>(mol_lin_w, mol_att_src, usrc);
    matvec_left<<<1, BLK, 0, stream>>>(mol_lin_w, mol_att_dst, vvec);
    node_dot<<<gridNodeWave, BLK, 0, stream>>>(B1, usrc, nullptr, dotr, nullptr, N);

    const int gridGWave = cdiv(G, 4);
    const int gridGThr = cdiv(G, BLK);
    dim3 gridG3(cdiv(NH3, 64), cdiv(G, 64));
    dim3 gridGH(cdiv(NH, 64), cdiv(G, 64));
    for (int t = 0; t < 2; ++t) {
        node_dot<<<gridGWave, BLK, 0, stream>>>(gout, vvec, nullptr, ddot, nullptr, G);
        mol_node_logit<<<gridNodeThr, BLK, 0, stream>>>(dotr, ddot, batch, nlog, N);
        fill_u32<<<gridGThr, BLK, 0, stream>>>(smax, ENC_NEG_INF, G);
        fill_f32<<<gridGThr, BLK, 0, stream>>>(ssum, 0.f, G);
        seg_max_k<<<gridNodeThr, BLK, 0, stream>>>(nlog, batch, smax, N);
        seg_exp_k<<<gridNodeThr, BLK, 0, stream>>>(nlog, batch, smax, nexp, ssum, N);
        fill_f32<<<cdiv(GHtot, BLK), BLK, 0, stream>>>(hraw_g, 0.f, GHtot);
        scatter_rows_alpha<<<gridNodeWave, BLK, 0, stream>>>(B1, nexp, ssum, batch, hraw_g, N);
        gemm_nt<<<gridGH, BLK, 0, stream>>>(hraw_g, mol_lin_w, mol_bias, h_g, G, NH, NH, NH, 2);
        gemm_nt<<<gridG3, BLK, 0, stream>>>(h_g, mol_gru_w_ih, nullptr, gig, G, NH, NH3, NH, 0);
        gemm_nt<<<gridG3, BLK, 0, stream>>>(gout, mol_gru_w_hh, nullptr, ghg, G, NH, NH3, NH, 0);
        gru_combine<<<cdiv(GHtot, BLK), BLK, 0, stream>>>(gig, ghg, mol_gru_b_ih, mol_gru_b_hh,
                                                          gout, gout, G);
    }

    // ---------- readout ----------
    gemm_nt<<<gridGH, BLK, 0, stream>>>(gout, lin2_w, lin2_b, emb, G, NH, NH, NH, 0);
    dim3 gridFc(cdiv(NTASK, 64), cdiv(G, 64));
    gemm_nt<<<gridFc, BLK, 0, stream>>>(emb, fc_w, fc_b, (float*)d_out, G, NH, NTASK, NH, 0);
}

// Round 3
// 7166.893 us; speedup vs baseline: 2.7230x; 2.7230x over previous
//
#include <hip/hip_runtime.h>
#include <math.h>
#include <stdio.h>
#include <stdint.h>

#define NH 256
#define NH3 768
#define FNODE 133
#define FEDGE 7
#define LDW_GATE1 263   // H + F_EDGE
#define NGRAPH 4096
#define NTASK 12
#define SLOPE 0.01f
#define ENC_NEG_INF 0x007FFFFFu
#define CHUNK 12500
#define PADK 40         // bf16 elems per LDS row: 32 + 8 pad (80B stride, 16B aligned)

typedef __attribute__((ext_vector_type(4))) float f32x4;
typedef __attribute__((ext_vector_type(8))) __bf16 bf16x8;
typedef unsigned short ushort_t;

static __device__ __forceinline__ float lrelu_f(float x) { return x > 0.f ? x : SLOPE * x; }

static __device__ __forceinline__ unsigned fenc(float x) {
    unsigned u = __float_as_uint(x);
    return (u & 0x80000000u) ? ~u : (u | 0x80000000u);
}
static __device__ __forceinline__ float fdec(unsigned u) {
    u = (u & 0x80000000u) ? (u & 0x7FFFFFFFu) : ~u;
    return __uint_as_float(u);
}
static __device__ __forceinline__ float bf2f(ushort_t u) {
    return __uint_as_float(((unsigned)u) << 16);
}

// ---------------- MFMA bf16 GEMM core ----------------
// C[M,Nout] = act(A[M,K(f32)] @ W[Nout, ldW(f32)]^T + bias)
// ACT: 0 none, 1 lrelu, 2 elu ; OB: 0 f32 out, 1 bf16(ushort) out
template<int ACT, int OB>
static __device__ __forceinline__ void gemm_core(
    __bf16* As, __bf16* Ws,
    const float* __restrict__ A, const float* __restrict__ W,
    const float* __restrict__ bias, void* __restrict__ Cout,
    int M, int K, int Nout, int ldW)
{
    const int bm = blockIdx.y * 128;
    const int bn = blockIdx.x * 64;
    const int tid = threadIdx.x;
    const int wv = tid >> 6, lane = tid & 63;
    const int l15 = lane & 15, l4 = lane >> 4;
    const bool kvec = ((K & 31) == 0);
    const bool wvec = kvec && ((ldW & 3) == 0);

    f32x4 acc[2][4];
#pragma unroll
    for (int g = 0; g < 2; ++g)
#pragma unroll
        for (int c = 0; c < 4; ++c) acc[g][c] = (f32x4){0.f, 0.f, 0.f, 0.f};

    for (int k0 = 0; k0 < K; k0 += 32) {
        // stage A: 128 rows x 32 k ; thread: row=tid>>1, khalf=(tid&1)*16
        {
            const int r = tid >> 1, kh = (tid & 1) * 16;
            const int ga = bm + r;
            __bf16* dst = &As[r * PADK + kh];
            if (ga < M && kvec) {
                const float4* ap4 = reinterpret_cast<const float4*>(A + (size_t)ga * K + k0 + kh);
#pragma unroll
                for (int q = 0; q < 4; ++q) {
                    float4 v = ap4[q];
                    dst[q * 4 + 0] = (__bf16)v.x; dst[q * 4 + 1] = (__bf16)v.y;
                    dst[q * 4 + 2] = (__bf16)v.z; dst[q * 4 + 3] = (__bf16)v.w;
                }
            } else {
                const float* ap = A + (size_t)ga * K + k0 + kh;
#pragma unroll
                for (int j = 0; j < 16; ++j) {
                    int gk = k0 + kh + j;
                    float v = (ga < M && gk < K) ? ap[j] : 0.f;
                    dst[j] = (__bf16)v;
                }
            }
        }
        // stage W: 64 rows x 32 k ; thread: row=tid>>2, kq=(tid&3)*8
        {
            const int r = tid >> 2, kq = (tid & 3) * 8;
            const int gw = bn + r;
            __bf16* dst = &Ws[r * PADK + kq];
            if (gw < Nout && wvec) {
                const float4* wp4 = reinterpret_cast<const float4*>(W + (size_t)gw * ldW + k0 + kq);
#pragma unroll
                for (int q = 0; q < 2; ++q) {
                    float4 v = wp4[q];
                    dst[q * 4 + 0] = (__bf16)v.x; dst[q * 4 + 1] = (__bf16)v.y;
                    dst[q * 4 + 2] = (__bf16)v.z; dst[q * 4 + 3] = (__bf16)v.w;
                }
            } else {
                const float* wp = W + (size_t)gw * ldW + k0 + kq;
#pragma unroll
                for (int j = 0; j < 8; ++j) {
                    int gk = k0 + kq + j;
                    float v = (gw < Nout && gk < K) ? wp[j] : 0.f;
                    dst[j] = (__bf16)v;
                }
            }
        }
        __syncthreads();
        bf16x8 af[2], wf[4];
        af[0] = *reinterpret_cast<const bf16x8*>(&As[(wv * 32 + l15) * PADK + l4 * 8]);
        af[1] = *reinterpret_cast<const bf16x8*>(&As[(wv * 32 + 16 + l15) * PADK + l4 * 8]);
#pragma unroll
        for (int c = 0; c < 4; ++c)
            wf[c] = *reinterpret_cast<const bf16x8*>(&Ws[(c * 16 + l15) * PADK + l4 * 8]);
#pragma unroll
        for (int g = 0; g < 2; ++g)
#pragma unroll
            for (int c = 0; c < 4; ++c)
                acc[g][c] = __builtin_amdgcn_mfma_f32_16x16x32_bf16(af[g], wf[c], acc[g][c], 0, 0, 0);
        __syncthreads();
    }

#pragma unroll
    for (int g = 0; g < 2; ++g) {
#pragma unroll
        for (int c = 0; c < 4; ++c) {
            int gc = bn + c * 16 + l15;
            if (gc >= Nout) continue;
            float bv = bias ? bias[gc] : 0.f;
#pragma unroll
            for (int q = 0; q < 4; ++q) {
                int gr = bm + wv * 32 + g * 16 + l4 * 4 + q;
                if (gr >= M) continue;
                float v = acc[g][c][q] + bv;
                if (ACT == 1) v = lrelu_f(v);
                else if (ACT == 2) v = (v > 0.f ? v : expm1f(v));
                size_t off = (size_t)gr * Nout + gc;
                if (OB) {
                    __bf16 b = (__bf16)v;
                    ((ushort_t*)Cout)[off] = *reinterpret_cast<ushort_t*>(&b);
                } else {
                    ((float*)Cout)[off] = v;
                }
            }
        }
    }
}

template<int ACT, int OB>
__global__ __launch_bounds__(256) void gemm_mfma(
    const float* __restrict__ A, const float* __restrict__ W,
    const float* __restrict__ bias, void* __restrict__ Cout,
    int M, int K, int Nout, int ldW)
{
    __shared__ __bf16 As[128 * PADK];
    __shared__ __bf16 Ws[64 * PADK];
    gemm_core<ACT, OB>(As, Ws, A, W, bias, Cout, M, K, Nout, ldW);
}

// dual GEMM: z=0 -> C0 = A0@W0^T ; z=1 -> C1 = A1@W1^T  (no bias/act), ldW=K
template<int ACT, int OB>
__global__ __launch_bounds__(256) void gemm_mfma2(
    const float* __restrict__ A0, const float* __restrict__ A1,
    const float* __restrict__ W0, const float* __restrict__ W1,
    void* __restrict__ C0, void* __restrict__ C1,
    int M, int K, int Nout)
{
    __shared__ __bf16 As[128 * PADK];
    __shared__ __bf16 Ws[64 * PADK];
    if (blockIdx.z == 0)
        gemm_core<ACT, OB>(As, Ws, A0, W0, nullptr, C0, M, K, Nout, K);
    else
        gemm_core<ACT, OB>(As, Ws, A1, W1, nullptr, C1, M, K, Nout, K);
}

// ---------------- fp32 fallback GEMM (tiny shapes only) ----------------
__global__ __launch_bounds__(256) void gemm_nt(
    const float* __restrict__ A, const float* __restrict__ W,
    const float* __restrict__ bias, float* __restrict__ C,
    int M, int K, int Nout, int ldW, int act)
{
    __shared__ float As[16][65];
    __shared__ float Ws[16][65];
    const int bm = blockIdx.y * 64;
    const int bn = blockIdx.x * 64;
    const int tid = threadIdx.x;
    const int tr = tid >> 4, tc = tid & 15;
    const int lrow = tid >> 2, lk = (tid & 3) * 4;
    float acc[4][4] = {};
    for (int k0 = 0; k0 < K; k0 += 16) {
#pragma unroll
        for (int j = 0; j < 4; ++j) {
            int gk = k0 + lk + j;
            int ga = bm + lrow;
            As[lk + j][lrow] = (ga < M && gk < K) ? A[(size_t)ga * K + gk] : 0.f;
            int gw = bn + lrow;
            Ws[lk + j][lrow] = (gw < Nout && gk < K) ? W[(size_t)gw * ldW + gk] : 0.f;
        }
        __syncthreads();
#pragma unroll
        for (int kk = 0; kk < 16; ++kk) {
            float av[4], bv[4];
#pragma unroll
            for (int i = 0; i < 4; ++i) av[i] = As[kk][tr * 4 + i];
#pragma unroll
            for (int i = 0; i < 4; ++i) bv[i] = Ws[kk][tc * 4 + i];
#pragma unroll
            for (int i = 0; i < 4; ++i)
#pragma unroll
                for (int j = 0; j < 4; ++j) acc[i][j] += av[i] * bv[j];
        }
        __syncthreads();
    }
#pragma unroll
    for (int i = 0; i < 4; ++i) {
        int m = bm + tr * 4 + i;
        if (m >= M) continue;
#pragma unroll
        for (int j = 0; j < 4; ++j) {
            int n = bn + tc * 4 + j;
            if (n >= Nout) continue;
            float v = acc[i][j];
            if (bias) v += bias[n];
            if (act == 1) v = lrelu_f(v);
            else if (act == 2) v = (v > 0.f ? v : expm1f(v));
            C[(size_t)m * Nout + n] = v;
        }
    }
}

__global__ void fill_f32(float* p, float v, size_t n) {
    size_t i = (size_t)blockIdx.x * 256 + threadIdx.x;
    if (i < n) p[i] = v;
}
__global__ void fill_u32(unsigned* p, unsigned v, size_t n) {
    size_t i = (size_t)blockIdx.x * 256 + threadIdx.x;
    if (i < n) p[i] = v;
}
__global__ void relu_inplace(float* p, size_t n) {
    size_t i = (size_t)blockIdx.x * 256 + threadIdx.x;
    if (i < n) p[i] = fmaxf(p[i], 0.f);
}

// o1[n] = X[n,:]·v1 ; o2[n] = X[n,:]·v2 (optional)
__global__ __launch_bounds__(256) void node_dot(
    const float* __restrict__ X, const float* __restrict__ v1, const float* __restrict__ v2,
    float* __restrict__ o1, float* __restrict__ o2, int M)
{
    __shared__ float s1[NH], s2[NH];
    int tid = threadIdx.x;
    s1[tid] = v1[tid];
    s2[tid] = v2 ? v2[tid] : 0.f;
    __syncthreads();
    int wv = tid >> 6, lane = tid & 63;
    for (int n = blockIdx.x * 4 + wv; n < M; n += gridDim.x * 4) {
        float a1 = 0.f, a2 = 0.f;
#pragma unroll
        for (int i = 0; i < 4; ++i) {
            int hh = i * 64 + lane;
            float xv = X[(size_t)n * NH + hh];
            a1 += xv * s1[hh];
            a2 += xv * s2[hh];
        }
#pragma unroll
        for (int off = 32; off; off >>= 1) { a1 += __shfl_xor(a1, off); a2 += __shfl_xor(a2, off); }
        if (lane == 0) { o1[n] = a1; if (o2) o2[n] = a2; }
    }
}

// per-edge GATEConv logit
__global__ __launch_bounds__(256) void gate_edge_logit(
    const float* __restrict__ nodepart, const float* __restrict__ edge_attr,
    const float* __restrict__ gate_lin1_w, const float* __restrict__ att_l,
    const float* __restrict__ dotr, const int* __restrict__ src, const int* __restrict__ dst,
    float* __restrict__ logit, int E)
{
    __shared__ float sW[NH * FEDGE];
    __shared__ float sAl[NH];
    int tid = threadIdx.x;
    for (int i = tid; i < NH * FEDGE; i += 256)
        sW[i] = gate_lin1_w[(size_t)(i / FEDGE) * LDW_GATE1 + NH + (i % FEDGE)];
    sAl[tid] = att_l[tid];
    __syncthreads();
    int wv = tid >> 6, lane = tid & 63;
    for (int e = blockIdx.x * 4 + wv; e < E; e += gridDim.x * 4) {
        int s = src[e], d = dst[e];
        float ea[FEDGE];
#pragma unroll
        for (int f = 0; f < FEDGE; ++f) ea[f] = edge_attr[(size_t)e * FEDGE + f];
        float acc = 0.f;
#pragma unroll
        for (int i = 0; i < 4; ++i) {
            int hh = i * 64 + lane;
            float v = nodepart[(size_t)s * NH + hh];
#pragma unroll
            for (int f = 0; f < FEDGE; ++f) v += ea[f] * sW[hh * FEDGE + f];
            v = lrelu_f(v);
            acc += v * sAl[hh];
        }
#pragma unroll
        for (int off = 32; off; off >>= 1) acc += __shfl_xor(acc, off);
        if (lane == 0) logit[e] = lrelu_f(acc + dotr[d]);
    }
}

__global__ void atom_edge_logit(
    const float* __restrict__ asrc, const float* __restrict__ adst,
    const int* __restrict__ src, const int* __restrict__ dst, float* __restrict__ logit, int E)
{
    int i = blockIdx.x * 256 + threadIdx.x;
    if (i < E) logit[i] = lrelu_f(asrc[src[i]] + adst[dst[i]]);
}

__global__ void seg_max_k(const float* __restrict__ logit, const int* __restrict__ seg,
                          unsigned* __restrict__ menc, int n)
{
    int i = blockIdx.x * 256 + threadIdx.x;
    if (i < n) atomicMax(&menc[seg[i]], fenc(logit[i]));
}
__global__ void seg_exp_k(const float* __restrict__ logit, const int* __restrict__ seg,
                          const unsigned* __restrict__ menc, float* __restrict__ ex,
                          float* __restrict__ ssum, int n)
{
    int i = blockIdx.x * 256 + threadIdx.x;
    if (i < n) {
        float m = fdec(menc[seg[i]]);
        float e = expf(logit[i] - m);
        ex[i] = e;
        atomicAdd(&ssum[seg[i]], e);
    }
}

// hraw[dst] += V[src] * (ex[e]/(ssum[dst]+1e-16)) ; wave per edge
__global__ __launch_bounds__(256) void scatter_msg(
    const float* __restrict__ V, const float* __restrict__ ex, const float* __restrict__ ssum,
    const int* __restrict__ src, const int* __restrict__ dst, float* __restrict__ hout, int E)
{
    int wv = threadIdx.x >> 6, lane = threadIdx.x & 63;
    for (int e = blockIdx.x * 4 + wv; e < E; e += gridDim.x * 4) {
        int s = src[e], d = dst[e];
        float alpha = ex[e] / (ssum[d] + 1e-16f);
#pragma unroll
        for (int i = 0; i < 4; ++i) {
            int hh = i * 64 + lane;
            atomicAdd(&hout[(size_t)d * NH + hh], V[(size_t)s * NH + hh] * alpha);
        }
    }
}

__global__ __launch_bounds__(256) void scatter_rows(
    const float* __restrict__ X, const int* __restrict__ seg, float* __restrict__ out, int M)
{
    int wv = threadIdx.x >> 6, lane = threadIdx.x & 63;
    for (int n = blockIdx.x * 4 + wv; n < M; n += gridDim.x * 4) {
        int b = seg[n];
#pragma unroll
        for (int i = 0; i < 4; ++i) {
            int hh = i * 64 + lane;
            atomicAdd(&out[(size_t)b * NH + hh], X[(size_t)n * NH + hh]);
        }
    }
}

__global__ __launch_bounds__(256) void scatter_rows_alpha(
    const float* __restrict__ X, const float* __restrict__ ex, const float* __restrict__ ssum,
    const int* __restrict__ seg, float* __restrict__ out, int M)
{
    int wv = threadIdx.x >> 6, lane = threadIdx.x & 63;
    for (int n = blockIdx.x * 4 + wv; n < M; n += gridDim.x * 4) {
        int b = seg[n];
        float alpha = ex[n] / (ssum[b] + 1e-16f);
#pragma unroll
        for (int i = 0; i < 4; ++i) {
            int hh = i * 64 + lane;
            atomicAdd(&out[(size_t)b * NH + hh], X[(size_t)n * NH + hh] * alpha);
        }
    }
}

__global__ void mol_node_logit(
    const float* __restrict__ asrc, const float* __restrict__ dstdot,
    const int* __restrict__ batch, float* __restrict__ logit, int n)
{
    int i = blockIdx.x * 256 + threadIdx.x;
    if (i < n) logit[i] = lrelu_f(asrc[i] + dstdot[batch[i]]);
}

// v[j] = (W^T a)[j]
__global__ __launch_bounds__(256) void matvec_left(
    const float* __restrict__ Wm, const float* __restrict__ a, float* __restrict__ v)
{
    int j = threadIdx.x;
    float s = 0.f;
    for (int i = 0; i < NH; ++i) s += a[i] * Wm[(size_t)i * NH + j];
    v[j] = s;
}

// GRU combine (gates r,z,n) + ReLU ; gi/gh are bf16
__global__ __launch_bounds__(256) void gru_combine(
    const ushort_t* __restrict__ gi, const ushort_t* __restrict__ gh,
    const float* __restrict__ b_ih, const float* __restrict__ b_hh,
    const float* __restrict__ hprev, float* __restrict__ out, int M)
{
    size_t idx = (size_t)blockIdx.x * 256 + threadIdx.x;
    if (idx >= (size_t)M * NH) return;
    int n = (int)(idx >> 8), j = (int)(idx & (NH - 1));
    size_t b3 = (size_t)n * NH3;
    float ir = bf2f(gi[b3 + j]) + b_ih[j];
    float iz = bf2f(gi[b3 + NH + j]) + b_ih[NH + j];
    float inn = bf2f(gi[b3 + 2 * NH + j]) + b_ih[2 * NH + j];
    float hr = bf2f(gh[b3 + j]) + b_hh[j];
    float hz = bf2f(gh[b3 + NH + j]) + b_hh[NH + j];
    float hn = bf2f(gh[b3 + 2 * NH + j]) + b_hh[2 * NH + j];
    float r = 1.f / (1.f + expf(-(ir + hr)));
    float z = 1.f / (1.f + expf(-(iz + hz)));
    float nn = tanhf(inn + r * hn);
    float hv = (1.f - z) * nn + z * hprev[idx];
    out[idx] = fmaxf(hv, 0.f);
}

extern "C" void kernel_launch(void* const* d_in, const int* in_sizes, int n_in,
                              void* d_out, int out_size, void* d_ws, size_t ws_size,
                              hipStream_t stream)
{
    const float* x          = (const float*)d_in[0];
    const float* edge_attr  = (const float*)d_in[1];
    const float* lin1_w     = (const float*)d_in[2];
    const float* lin1_b     = (const float*)d_in[3];
    const float* gate_att_l = (const float*)d_in[4];
    const float* gate_att_r = (const float*)d_in[5];
    const float* gate_lin1_w= (const float*)d_in[6];
    const float* gate_lin2_w= (const float*)d_in[7];
    const float* gate_bias  = (const float*)d_in[8];
    const float* atom_lin_w = (const float*)d_in[9];
    const float* atom_att_src=(const float*)d_in[10];
    const float* atom_att_dst=(const float*)d_in[11];
    const float* atom_bias  = (const float*)d_in[12];
    const float* gru_w_ih   = (const float*)d_in[13];
    const float* gru_w_hh   = (const float*)d_in[14];
    const float* gru_b_ih   = (const float*)d_in[15];
    const float* gru_b_hh   = (const float*)d_in[16];
    const float* mol_lin_w  = (const float*)d_in[17];
    const float* mol_att_src= (const float*)d_in[18];
    const float* mol_att_dst= (const float*)d_in[19];
    const float* mol_bias   = (const float*)d_in[20];
    const float* mol_gru_w_ih=(const float*)d_in[21];
    const float* mol_gru_w_hh=(const float*)d_in[22];
    const float* mol_gru_b_ih=(const float*)d_in[23];
    const float* mol_gru_b_hh=(const float*)d_in[24];
    const float* lin2_w     = (const float*)d_in[25];
    const float* lin2_b     = (const float*)d_in[26];
    const float* fc_w       = (const float*)d_in[27];
    const float* fc_b       = (const float*)d_in[28];
    const int*   edge_index = (const int*)d_in[29];
    const int*   batch      = (const int*)d_in[30];

    const int N = in_sizes[0] / FNODE;
    const int E = in_sizes[1] / FEDGE;
    const int G = NGRAPH;
    const int* src = edge_index;
    const int* dst = edge_index + E;

    float* w = (float*)d_ws;
    size_t o = 0;
    auto alloc = [&](size_t cnt) { size_t r = o; o += cnt; return r; };
    const size_t o_B1   = alloc((size_t)N * NH);          // x0 -> xcur (in-place GRU)
    const size_t o_B2   = alloc((size_t)N * NH);          // nodepart -> hraw ; mol-phase buffers
    const size_t o_B3   = alloc((size_t)CHUNK * 1024);    // tmp f32(256) + gi bf16(768) + gh bf16(768)
    const size_t o_elog = alloc((size_t)E);
    const size_t o_eexp = alloc((size_t)E);
    const size_t o_dotr = alloc((size_t)N);
    const size_t o_adst = alloc((size_t)N);
    const size_t o_smax = alloc((size_t)N);               // unsigned
    const size_t o_ssum = alloc((size_t)N);
    const size_t o_nlog = alloc((size_t)N);
    const size_t o_nexp = alloc((size_t)N);
    const size_t o_vvec = alloc((size_t)NH);
    const size_t o_usrc = alloc((size_t)NH);
    const size_t o_udst = alloc((size_t)NH);
    const size_t o_ddot = alloc((size_t)G);
    if (o * sizeof(float) > ws_size) {
        fprintf(stderr, "kernel_launch: ws too small: need %zu have %zu\n", o * 4, ws_size);
        return;
    }

    float* B1   = w + o_B1;
    float* B2   = w + o_B2;
    float* B3   = w + o_B3;
    float* elog = w + o_elog;
    float* eexp = w + o_eexp;
    float* dotr = w + o_dotr;
    float* adst = w + o_adst;
    unsigned* smax = (unsigned*)(w + o_smax);
    float* ssum = w + o_ssum;
    float* nlog = w + o_nlog;
    float* nexp = w + o_nexp;
    float* vvec = w + o_vvec;
    float* usrc = w + o_usrc;
    float* udst = w + o_udst;
    float* ddot = w + o_ddot;

    // mol-phase sub-buffers inside B2 (node-phase hraw dead by then)
    float*    gout   = B2;                                   // G*NH f32
    float*    hraw_g = B2 + (size_t)G * NH;                  // G*NH f32
    float*    h_g    = B2 + (size_t)2 * G * NH;              // G*NH f32
    ushort_t* gig    = (ushort_t*)(B2 + (size_t)3 * G * NH);           // G*NH3 bf16
    ushort_t* ghg    = (ushort_t*)(B2 + (size_t)3 * G * NH + (size_t)G * NH3 / 2); // G*NH3 bf16
    float*    emb    = B2 + (size_t)3 * G * NH + (size_t)G * NH3;      // G*NH f32

    const int BLK = 256;
    auto cdiv = [](size_t a, size_t b) { return (int)((a + b - 1) / b); };
    const int gridEdgeWave = cdiv(E, 4);
    const int gridNodeWave = cdiv(N, 4);
    const int gridEdgeThr = cdiv(E, BLK);
    const int gridNodeThr = cdiv(N, BLK);
    const size_t NHtot = (size_t)N * NH;

    // Per-layer tail: h = elu(hraw@Wh^T + bh) ; GRU(h, xbuf) -> xbuf (chunked, in place)
    auto run_tail = [&](const float* Wh, const float* bh,
                        const float* wih, const float* whh,
                        const float* bih, const float* bhh, float* xbuf) {
        float*    tmp = B3;                                     // CHUNK*NH f32
        ushort_t* gi  = (ushort_t*)(B3 + (size_t)CHUNK * NH);   // CHUNK*NH3 bf16
        ushort_t* gh  = (ushort_t*)(B3 + (size_t)CHUNK * 640);  // CHUNK*NH3 bf16
        for (int c0 = 0; c0 < N; c0 += CHUNK) {
            int mc = (N - c0) < CHUNK ? (N - c0) : CHUNK;
            dim3 gH(4, cdiv(mc, 128));
            dim3 gD(12, cdiv(mc, 128), 2);
            gemm_mfma<2, 0><<<gH, BLK, 0, stream>>>(B2 + (size_t)c0 * NH, Wh, bh, tmp, mc, NH, NH, NH);
            gemm_mfma2<0, 1><<<gD, BLK, 0, stream>>>(tmp, xbuf + (size_t)c0 * NH, wih, whh,
                                                     gi, gh, mc, NH, NH3);
            gru_combine<<<cdiv((size_t)mc * NH, BLK), BLK, 0, stream>>>(
                gi, gh, bih, bhh, xbuf + (size_t)c0 * NH, xbuf + (size_t)c0 * NH, mc);
        }
    };

    dim3 gridNH(4, cdiv(N, 128));

    // ---------- x0 = lrelu(x @ lin1_w^T + lin1_b) ----------
    gemm_mfma<1, 0><<<gridNH, BLK, 0, stream>>>(x, lin1_w, lin1_b, B1, N, FNODE, NH, FNODE);

    // ---------- GATEConv ----------
    gemm_mfma<0, 0><<<gridNH, BLK, 0, stream>>>(B1, gate_lin1_w, nullptr, B2, N, NH, NH, LDW_GATE1);
    node_dot<<<gridNodeWave, BLK, 0, stream>>>(B1, gate_att_r, nullptr, dotr, nullptr, N);
    gate_edge_logit<<<gridEdgeWave, BLK, 0, stream>>>(B2, edge_attr, gate_lin1_w, gate_att_l,
                                                      dotr, src, dst, elog, E);
    fill_u32<<<gridNodeThr, BLK, 0, stream>>>(smax, ENC_NEG_INF, N);
    fill_f32<<<gridNodeThr, BLK, 0, stream>>>(ssum, 0.f, N);
    seg_max_k<<<gridEdgeThr, BLK, 0, stream>>>(elog, dst, smax, E);
    seg_exp_k<<<gridEdgeThr, BLK, 0, stream>>>(elog, dst, smax, eexp, ssum, E);
    fill_f32<<<cdiv(NHtot, BLK), BLK, 0, stream>>>(B2, 0.f, NHtot);
    scatter_msg<<<gridEdgeWave, BLK, 0, stream>>>(B1, eexp, ssum, src, dst, B2, E);
    run_tail(gate_lin2_w, gate_bias, gru_w_ih, gru_w_hh, gru_b_ih, gru_b_hh, B1);

    // ---------- 3 GATConv layers ----------
    for (int l = 0; l < 3; ++l) {
        const float* wl = atom_lin_w + (size_t)l * NH * NH;
        matvec_left<<<1, BLK, 0, stream>>>(wl, atom_att_src + l * NH, usrc);
        matvec_left<<<1, BLK, 0, stream>>>(wl, atom_att_dst + l * NH, udst);
        node_dot<<<gridNodeWave, BLK, 0, stream>>>(B1, usrc, udst, dotr, adst, N);
        atom_edge_logit<<<gridEdgeThr, BLK, 0, stream>>>(dotr, adst, src, dst, elog, E);
        fill_u32<<<gridNodeThr, BLK, 0, stream>>>(smax, ENC_NEG_INF, N);
        fill_f32<<<gridNodeThr, BLK, 0, stream>>>(ssum, 0.f, N);
        seg_max_k<<<gridEdgeThr, BLK, 0, stream>>>(elog, dst, smax, E);
        seg_exp_k<<<gridEdgeThr, BLK, 0, stream>>>(elog, dst, smax, eexp, ssum, E);
        fill_f32<<<cdiv(NHtot, BLK), BLK, 0, stream>>>(B2, 0.f, NHtot);
        scatter_msg<<<gridEdgeWave, BLK, 0, stream>>>(B1, eexp, ssum, src, dst, B2, E);
        run_tail(wl, atom_bias + l * NH,
                 gru_w_ih + (size_t)(l + 1) * NH3 * NH, gru_w_hh + (size_t)(l + 1) * NH3 * NH,
                 gru_b_ih + (size_t)(l + 1) * NH3, gru_b_hh + (size_t)(l + 1) * NH3, B1);
    }

    // ---------- Molecule pooling ----------
    const size_t GHtot = (size_t)G * NH;
    fill_f32<<<cdiv(GHtot, BLK), BLK, 0, stream>>>(gout, 0.f, GHtot);
    scatter_rows<<<gridNodeWave, BLK, 0, stream>>>(B1, batch, gout, N);
    relu_inplace<<<cdiv(GHtot, BLK), BLK, 0, stream>>>(gout, GHtot);
    matvec_left<<<1, BLK, 0, stream>>>(mol_lin_w, mol_att_src, usrc);
    matvec_left<<<1, BLK, 0, stream>>>(mol_lin_w, mol_att_dst, vvec);
    node_dot<<<gridNodeWave, BLK, 0, stream>>>(B1, usrc, nullptr, dotr, nullptr, N);

    const int gridGWave = cdiv(G, 4);
    const int gridGThr = cdiv(G, BLK);
    dim3 gridGH(4, cdiv(G, 128));
    dim3 gridGD(12, cdiv(G, 128), 2);
    for (int t = 0; t < 2; ++t) {
        node_dot<<<gridGWave, BLK, 0, stream>>>(gout, vvec, nullptr, ddot, nullptr, G);
        mol_node_logit<<<gridNodeThr, BLK, 0, stream>>>(dotr, ddot, batch, nlog, N);
        fill_u32<<<gridGThr, BLK, 0, stream>>>(smax, ENC_NEG_INF, G);
        fill_f32<<<gridGThr, BLK, 0, stream>>>(ssum, 0.f, G);
        seg_max_k<<<gridNodeThr, BLK, 0, stream>>>(nlog, batch, smax, N);
        seg_exp_k<<<gridNodeThr, BLK, 0, stream>>>(nlog, batch, smax, nexp, ssum, N);
        fill_f32<<<cdiv(GHtot, BLK), BLK, 0, stream>>>(hraw_g, 0.f, GHtot);
        scatter_rows_alpha<<<gridNodeWave, BLK, 0, stream>>>(B1, nexp, ssum, batch, hraw_g, N);
        gemm_mfma<2, 0><<<gridGH, BLK, 0, stream>>>(hraw_g, mol_lin_w, mol_bias, h_g, G, NH, NH, NH);
        gemm_mfma2<0, 1><<<gridGD, BLK, 0, stream>>>(h_g, gout, mol_gru_w_ih, mol_gru_w_hh,
                                                     gig, ghg, G, NH, NH3);
        gru_combine<<<cdiv(GHtot, BLK), BLK, 0, stream>>>(gig, ghg, mol_gru_b_ih, mol_gru_b_hh,
                                                          gout, gout, G);
    }

    // ---------- readout ----------
    gemm_mfma<0, 0><<<gridGH, BLK, 0, stream>>>(gout, lin2_w, lin2_b, emb, G, NH, NH, NH);
    dim3 gridFc(1, cdiv(G, 64));
    gemm_nt<<<gridFc, BLK, 0, stream>>>(emb, fc_w, fc_b, (float*)d_out, G, NH, NTASK, NH, 0);
}

// Round 4
// 4792.432 us; speedup vs baseline: 4.0721x; 1.4955x over previous
//
#include <hip/hip_runtime.h>
#include <math.h>
#include <stdio.h>
#include <stdint.h>

#define NH 256
#define NH3 768
#define FNODE 133
#define FEDGE 7
#define LDW_GATE1 263   // H + F_EDGE
#define NGRAPH 4096
#define NTASK 12
#define SLOPE 0.01f
#define CHUNK 12000
#define PADK 40         // f16 elems per LDS row: 32 + 8 pad (80B stride, 16B aligned)

typedef __attribute__((ext_vector_type(4))) float f32x4;
typedef __attribute__((ext_vector_type(8))) _Float16 f16x8;

static __device__ __forceinline__ float lrelu_f(float x) { return x > 0.f ? x : SLOPE * x; }

// ---------------- MFMA fp16 GEMM core ----------------
// C[M,Nout] = act(A[M,K(f32)] @ W[Nout, ldW(f32)]^T + bias)
// ACT: 0 none, 1 lrelu, 2 elu ; OB: 0 f32 out, 1 fp16 out
template<int ACT, int OB>
static __device__ __forceinline__ void gemm_core(
    _Float16* As, _Float16* Ws,
    const float* __restrict__ A, const float* __restrict__ W,
    const float* __restrict__ bias, void* __restrict__ Cout,
    int M, int K, int Nout, int ldW)
{
    const int bm = blockIdx.y * 128;
    const int bn = blockIdx.x * 64;
    const int tid = threadIdx.x;
    const int wv = tid >> 6, lane = tid & 63;
    const int l15 = lane & 15, l4 = lane >> 4;
    const bool kvec = ((K & 31) == 0);
    const bool wvec = kvec && ((ldW & 3) == 0);

    f32x4 acc[2][4];
#pragma unroll
    for (int g = 0; g < 2; ++g)
#pragma unroll
        for (int c = 0; c < 4; ++c) acc[g][c] = (f32x4){0.f, 0.f, 0.f, 0.f};

    for (int k0 = 0; k0 < K; k0 += 32) {
        // stage A: 128 rows x 32 k ; thread: row=tid>>1, khalf=(tid&1)*16
        {
            const int r = tid >> 1, kh = (tid & 1) * 16;
            const int ga = bm + r;
            _Float16* dst = &As[r * PADK + kh];
            if (ga < M && kvec) {
                const float4* ap4 = reinterpret_cast<const float4*>(A + (size_t)ga * K + k0 + kh);
#pragma unroll
                for (int q = 0; q < 4; ++q) {
                    float4 v = ap4[q];
                    dst[q * 4 + 0] = (_Float16)v.x; dst[q * 4 + 1] = (_Float16)v.y;
                    dst[q * 4 + 2] = (_Float16)v.z; dst[q * 4 + 3] = (_Float16)v.w;
                }
            } else {
                const float* ap = A + (size_t)ga * K + k0 + kh;
#pragma unroll
                for (int j = 0; j < 16; ++j) {
                    int gk = k0 + kh + j;
                    float v = (ga < M && gk < K) ? ap[j] : 0.f;
                    dst[j] = (_Float16)v;
                }
            }
        }
        // stage W: 64 rows x 32 k ; thread: row=tid>>2, kq=(tid&3)*8
        {
            const int r = tid >> 2, kq = (tid & 3) * 8;
            const int gw = bn + r;
            _Float16* dst = &Ws[r * PADK + kq];
            if (gw < Nout && wvec) {
                const float4* wp4 = reinterpret_cast<const float4*>(W + (size_t)gw * ldW + k0 + kq);
#pragma unroll
                for (int q = 0; q < 2; ++q) {
                    float4 v = wp4[q];
                    dst[q * 4 + 0] = (_Float16)v.x; dst[q * 4 + 1] = (_Float16)v.y;
                    dst[q * 4 + 2] = (_Float16)v.z; dst[q * 4 + 3] = (_Float16)v.w;
                }
            } else {
                const float* wp = W + (size_t)gw * ldW + k0 + kq;
#pragma unroll
                for (int j = 0; j < 8; ++j) {
                    int gk = k0 + kq + j;
                    float v = (gw < Nout && gk < K) ? wp[j] : 0.f;
                    dst[j] = (_Float16)v;
                }
            }
        }
        __syncthreads();
        f16x8 af[2], wf[4];
        af[0] = *reinterpret_cast<const f16x8*>(&As[(wv * 32 + l15) * PADK + l4 * 8]);
        af[1] = *reinterpret_cast<const f16x8*>(&As[(wv * 32 + 16 + l15) * PADK + l4 * 8]);
#pragma unroll
        for (int c = 0; c < 4; ++c)
            wf[c] = *reinterpret_cast<const f16x8*>(&Ws[(c * 16 + l15) * PADK + l4 * 8]);
#pragma unroll
        for (int g = 0; g < 2; ++g)
#pragma unroll
            for (int c = 0; c < 4; ++c)
                acc[g][c] = __builtin_amdgcn_mfma_f32_16x16x32_f16(af[g], wf[c], acc[g][c], 0, 0, 0);
        __syncthreads();
    }

#pragma unroll
    for (int g = 0; g < 2; ++g) {
#pragma unroll
        for (int c = 0; c < 4; ++c) {
            int gc = bn + c * 16 + l15;
            if (gc >= Nout) continue;
            float bv = bias ? bias[gc] : 0.f;
#pragma unroll
            for (int q = 0; q < 4; ++q) {
                int gr = bm + wv * 32 + g * 16 + l4 * 4 + q;
                if (gr >= M) continue;
                float v = acc[g][c][q] + bv;
                if (ACT == 1) v = lrelu_f(v);
                else if (ACT == 2) v = (v > 0.f ? v : expm1f(v));
                size_t off = (size_t)gr * Nout + gc;
                if (OB) ((_Float16*)Cout)[off] = (_Float16)v;
                else    ((float*)Cout)[off] = v;
            }
        }
    }
}

template<int ACT, int OB>
__global__ __launch_bounds__(256) void gemm_mfma(
    const float* __restrict__ A, const float* __restrict__ W,
    const float* __restrict__ bias, void* __restrict__ Cout,
    int M, int K, int Nout, int ldW)
{
    __shared__ _Float16 As[128 * PADK];
    __shared__ _Float16 Ws[64 * PADK];
    gemm_core<ACT, OB>(As, Ws, A, W, bias, Cout, M, K, Nout, ldW);
}

// dual GEMM: z=0 -> C0 = A0@W0^T ; z=1 -> C1 = A1@W1^T  (no bias/act), ldW=K
template<int ACT, int OB>
__global__ __launch_bounds__(256) void gemm_mfma2(
    const float* __restrict__ A0, const float* __restrict__ A1,
    const float* __restrict__ W0, const float* __restrict__ W1,
    void* __restrict__ C0, void* __restrict__ C1,
    int M, int K, int Nout)
{
    __shared__ _Float16 As[128 * PADK];
    __shared__ _Float16 Ws[64 * PADK];
    if (blockIdx.z == 0)
        gemm_core<ACT, OB>(As, Ws, A0, W0, nullptr, C0, M, K, Nout, K);
    else
        gemm_core<ACT, OB>(As, Ws, A1, W1, nullptr, C1, M, K, Nout, K);
}

// ---------------- fp32 fallback GEMM (final 12-col fc only) ----------------
__global__ __launch_bounds__(256) void gemm_nt(
    const float* __restrict__ A, const float* __restrict__ W,
    const float* __restrict__ bias, float* __restrict__ C,
    int M, int K, int Nout, int ldW, int act)
{
    __shared__ float As[16][65];
    __shared__ float Ws[16][65];
    const int bm = blockIdx.y * 64;
    const int bn = blockIdx.x * 64;
    const int tid = threadIdx.x;
    const int tr = tid >> 4, tc = tid & 15;
    const int lrow = tid >> 2, lk = (tid & 3) * 4;
    float acc[4][4] = {};
    for (int k0 = 0; k0 < K; k0 += 16) {
#pragma unroll
        for (int j = 0; j < 4; ++j) {
            int gk = k0 + lk + j;
            int ga = bm + lrow;
            As[lk + j][lrow] = (ga < M && gk < K) ? A[(size_t)ga * K + gk] : 0.f;
            int gw = bn + lrow;
            Ws[lk + j][lrow] = (gw < Nout && gk < K) ? W[(size_t)gw * ldW + gk] : 0.f;
        }
        __syncthreads();
#pragma unroll
        for (int kk = 0; kk < 16; ++kk) {
            float av[4], bv[4];
#pragma unroll
            for (int i = 0; i < 4; ++i) av[i] = As[kk][tr * 4 + i];
#pragma unroll
            for (int i = 0; i < 4; ++i) bv[i] = Ws[kk][tc * 4 + i];
#pragma unroll
            for (int i = 0; i < 4; ++i)
#pragma unroll
                for (int j = 0; j < 4; ++j) acc[i][j] += av[i] * bv[j];
        }
        __syncthreads();
    }
#pragma unroll
    for (int i = 0; i < 4; ++i) {
        int m = bm + tr * 4 + i;
        if (m >= M) continue;
#pragma unroll
        for (int j = 0; j < 4; ++j) {
            int n = bn + tc * 4 + j;
            if (n >= Nout) continue;
            float v = acc[i][j];
            if (bias) v += bias[n];
            if (act == 1) v = lrelu_f(v);
            C[(size_t)m * Nout + n] = v;
        }
    }
}

// ---------------- CSR build ----------------
__global__ void zero_i32(int* p, int n) {
    int i = blockIdx.x * 256 + threadIdx.x;
    if (i < n) p[i] = 0;
}
__global__ void hist_dst(const int* __restrict__ dst, int* __restrict__ deg, int E) {
    int i = blockIdx.x * 256 + threadIdx.x;
    if (i < E) atomicAdd(&deg[dst[i]], 1);
}
// single block, 256 threads: exclusive scan deg[0..Nn) -> rowptr[0..Nn], copy to cursor
__global__ __launch_bounds__(256) void scan_rowptr(
    const int* __restrict__ deg, int* __restrict__ rowptr, int* __restrict__ cursor, int Nn)
{
    __shared__ int lds[256];
    const int t = threadIdx.x;
    const int C = (Nn + 255) / 256;
    const int lo = t * C, hi = min((t + 1) * C, Nn);
    int s = 0;
    for (int i = lo; i < hi; ++i) s += deg[i];
    lds[t] = s;
    __syncthreads();
    for (int off = 1; off < 256; off <<= 1) {
        int v = (t >= off) ? lds[t - off] : 0;
        __syncthreads();
        lds[t] += v;
        __syncthreads();
    }
    int run = lds[t] - s;   // exclusive prefix
    for (int i = lo; i < hi; ++i) {
        rowptr[i] = run; cursor[i] = run; run += deg[i];
    }
    if (lo < Nn && hi >= Nn) rowptr[Nn] = run;
}
__global__ void csr_scatter(const int* __restrict__ src, const int* __restrict__ dst,
                            int* __restrict__ cursor, int* __restrict__ esrc,
                            int* __restrict__ eidx, int E)
{
    int e = blockIdx.x * 256 + threadIdx.x;
    if (e < E) {
        int p = atomicAdd(&cursor[dst[e]], 1);
        esrc[p] = src[e];
        eidx[p] = e;
    }
}
// gptr[g] = first index i with batch[i] >= g (batch sorted); g in [0, G]
__global__ void gptr_build(const int* __restrict__ batch, int* __restrict__ gptr, int Nn, int G) {
    int g = blockIdx.x * 256 + threadIdx.x;
    if (g > G) return;
    int lo = 0, hi = Nn;
    while (lo < hi) { int mid = (lo + hi) >> 1; if (batch[mid] < g) lo = mid + 1; else hi = mid; }
    gptr[g] = lo;
}

// ---------------- fused attention aggregation (CSR, wave per dst) ----------------
// GAT: logit = lrelu(asrc[src] + adst[d]) ; hout[d] = sum alpha * X[src]
__global__ __launch_bounds__(256) void gat_agg_csr(
    const float* __restrict__ X, const float* __restrict__ asrc, const float* __restrict__ adst,
    const int* __restrict__ rowptr, const int* __restrict__ esrc,
    float* __restrict__ hout, int Nn)
{
    int wv = threadIdx.x >> 6, lane = threadIdx.x & 63;
    int d = blockIdx.x * 4 + wv;
    if (d >= Nn) return;
    int beg = rowptr[d], end = rowptr[d + 1];
    float a0 = 0.f, a1 = 0.f, a2 = 0.f, a3 = 0.f;
    if (beg < end) {
        float ad = adst[d];
        float m = -3.4e38f;
        for (int j = beg + lane; j < end; j += 64)
            m = fmaxf(m, lrelu_f(asrc[esrc[j]] + ad));
#pragma unroll
        for (int off = 32; off; off >>= 1) m = fmaxf(m, __shfl_xor(m, off));
        float s = 0.f;
        for (int j = beg + lane; j < end; j += 64)
            s += expf(lrelu_f(asrc[esrc[j]] + ad) - m);
#pragma unroll
        for (int off = 32; off; off >>= 1) s += __shfl_xor(s, off);
        float inv = 1.f / (s + 1e-16f);
        for (int j = beg; j < end; ++j) {
            int sj = esrc[j];
            float a = expf(lrelu_f(asrc[sj] + ad) - m) * inv;
            const float* xr = X + (size_t)sj * NH;
            a0 += a * xr[lane]; a1 += a * xr[64 + lane];
            a2 += a * xr[128 + lane]; a3 += a * xr[192 + lane];
        }
    }
    float* hr = hout + (size_t)d * NH;
    hr[lane] = a0; hr[64 + lane] = a1; hr[128 + lane] = a2; hr[192 + lane] = a3;
}

// GATE: logit precomputed in elog (original edge order), index via eidx
__global__ __launch_bounds__(256) void gate_agg_csr(
    const float* __restrict__ X, const float* __restrict__ elog,
    const int* __restrict__ rowptr, const int* __restrict__ esrc, const int* __restrict__ eidx,
    float* __restrict__ hout, int Nn)
{
    int wv = threadIdx.x >> 6, lane = threadIdx.x & 63;
    int d = blockIdx.x * 4 + wv;
    if (d >= Nn) return;
    int beg = rowptr[d], end = rowptr[d + 1];
    float a0 = 0.f, a1 = 0.f, a2 = 0.f, a3 = 0.f;
    if (beg < end) {
        float m = -3.4e38f;
        for (int j = beg + lane; j < end; j += 64)
            m = fmaxf(m, elog[eidx[j]]);
#pragma unroll
        for (int off = 32; off; off >>= 1) m = fmaxf(m, __shfl_xor(m, off));
        float s = 0.f;
        for (int j = beg + lane; j < end; j += 64)
            s += expf(elog[eidx[j]] - m);
#pragma unroll
        for (int off = 32; off; off >>= 1) s += __shfl_xor(s, off);
        float inv = 1.f / (s + 1e-16f);
        for (int j = beg; j < end; ++j) {
            int sj = esrc[j];
            float a = expf(elog[eidx[j]] - m) * inv;
            const float* xr = X + (size_t)sj * NH;
            a0 += a * xr[lane]; a1 += a * xr[64 + lane];
            a2 += a * xr[128 + lane]; a3 += a * xr[192 + lane];
        }
    }
    float* hr = hout + (size_t)d * NH;
    hr[lane] = a0; hr[64 + lane] = a1; hr[128 + lane] = a2; hr[192 + lane] = a3;
}

// mol: wave per graph; nodes contiguous [gptr[g], gptr[g+1]); logit = lrelu(dotr[i]+ddot[g])
__global__ __launch_bounds__(256) void mol_agg_csr(
    const float* __restrict__ X, const float* __restrict__ dotr, const float* __restrict__ ddot,
    const int* __restrict__ gptr, float* __restrict__ hout, int G)
{
    int wv = threadIdx.x >> 6, lane = threadIdx.x & 63;
    int g = blockIdx.x * 4 + wv;
    if (g >= G) return;
    int beg = gptr[g], end = gptr[g + 1];
    float a0 = 0.f, a1 = 0.f, a2 = 0.f, a3 = 0.f;
    if (beg < end) {
        float dg = ddot[g];
        float m = -3.4e38f;
        for (int i = beg + lane; i < end; i += 64)
            m = fmaxf(m, lrelu_f(dotr[i] + dg));
#pragma unroll
        for (int off = 32; off; off >>= 1) m = fmaxf(m, __shfl_xor(m, off));
        float s = 0.f;
        for (int i = beg + lane; i < end; i += 64)
            s += expf(lrelu_f(dotr[i] + dg) - m);
#pragma unroll
        for (int off = 32; off; off >>= 1) s += __shfl_xor(s, off);
        float inv = 1.f / (s + 1e-16f);
        for (int i = beg; i < end; ++i) {
            float a = expf(lrelu_f(dotr[i] + dg) - m) * inv;
            const float* xr = X + (size_t)i * NH;
            a0 += a * xr[lane]; a1 += a * xr[64 + lane];
            a2 += a * xr[128 + lane]; a3 += a * xr[192 + lane];
        }
    }
    float* hr = hout + (size_t)g * NH;
    hr[lane] = a0; hr[64 + lane] = a1; hr[128 + lane] = a2; hr[192 + lane] = a3;
}

// gout[g] = relu(sum over nodes of graph g of X[i])
__global__ __launch_bounds__(256) void graph_sum_relu(
    const float* __restrict__ X, const int* __restrict__ gptr, float* __restrict__ out, int G)
{
    int wv = threadIdx.x >> 6, lane = threadIdx.x & 63;
    int g = blockIdx.x * 4 + wv;
    if (g >= G) return;
    int beg = gptr[g], end = gptr[g + 1];
    float a0 = 0.f, a1 = 0.f, a2 = 0.f, a3 = 0.f;
    for (int i = beg; i < end; ++i) {
        const float* xr = X + (size_t)i * NH;
        a0 += xr[lane]; a1 += xr[64 + lane]; a2 += xr[128 + lane]; a3 += xr[192 + lane];
    }
    float* hr = out + (size_t)g * NH;
    hr[lane] = fmaxf(a0, 0.f); hr[64 + lane] = fmaxf(a1, 0.f);
    hr[128 + lane] = fmaxf(a2, 0.f); hr[192 + lane] = fmaxf(a3, 0.f);
}

// o1[n] = X[n,:]·v1 ; o2[n] = X[n,:]·v2 (optional)
__global__ __launch_bounds__(256) void node_dot(
    const float* __restrict__ X, const float* __restrict__ v1, const float* __restrict__ v2,
    float* __restrict__ o1, float* __restrict__ o2, int M)
{
    __shared__ float s1[NH], s2[NH];
    int tid = threadIdx.x;
    s1[tid] = v1[tid];
    s2[tid] = v2 ? v2[tid] : 0.f;
    __syncthreads();
    int wv = tid >> 6, lane = tid & 63;
    for (int n = blockIdx.x * 4 + wv; n < M; n += gridDim.x * 4) {
        float a1 = 0.f, a2 = 0.f;
#pragma unroll
        for (int i = 0; i < 4; ++i) {
            int hh = i * 64 + lane;
            float xv = X[(size_t)n * NH + hh];
            a1 += xv * s1[hh];
            a2 += xv * s2[hh];
        }
#pragma unroll
        for (int off = 32; off; off >>= 1) { a1 += __shfl_xor(a1, off); a2 += __shfl_xor(a2, off); }
        if (lane == 0) { o1[n] = a1; if (o2) o2[n] = a2; }
    }
}

// per-edge GATEConv logit
__global__ __launch_bounds__(256) void gate_edge_logit(
    const float* __restrict__ nodepart, const float* __restrict__ edge_attr,
    const float* __restrict__ gate_lin1_w, const float* __restrict__ att_l,
    const float* __restrict__ dotr, const int* __restrict__ src, const int* __restrict__ dst,
    float* __restrict__ logit, int E)
{
    __shared__ float sW[NH * FEDGE];
    __shared__ float sAl[NH];
    int tid = threadIdx.x;
    for (int i = tid; i < NH * FEDGE; i += 256)
        sW[i] = gate_lin1_w[(size_t)(i / FEDGE) * LDW_GATE1 + NH + (i % FEDGE)];
    sAl[tid] = att_l[tid];
    __syncthreads();
    int wv = tid >> 6, lane = tid & 63;
    for (int e = blockIdx.x * 4 + wv; e < E; e += gridDim.x * 4) {
        int s = src[e], d = dst[e];
        float ea[FEDGE];
#pragma unroll
        for (int f = 0; f < FEDGE; ++f) ea[f] = edge_attr[(size_t)e * FEDGE + f];
        float acc = 0.f;
#pragma unroll
        for (int i = 0; i < 4; ++i) {
            int hh = i * 64 + lane;
            float v = nodepart[(size_t)s * NH + hh];
#pragma unroll
            for (int f = 0; f < FEDGE; ++f) v += ea[f] * sW[hh * FEDGE + f];
            v = lrelu_f(v);
            acc += v * sAl[hh];
        }
#pragma unroll
        for (int off = 32; off; off >>= 1) acc += __shfl_xor(acc, off);
        if (lane == 0) logit[e] = lrelu_f(acc + dotr[d]);
    }
}

// v[j] = (W^T a)[j]
__global__ __launch_bounds__(256) void matvec_left(
    const float* __restrict__ Wm, const float* __restrict__ a, float* __restrict__ v)
{
    int j = threadIdx.x;
    float s = 0.f;
    for (int i = 0; i < NH; ++i) s += a[i] * Wm[(size_t)i * NH + j];
    v[j] = s;
}

// GRU combine (gates r,z,n) + ReLU ; gi/gh are fp16
__global__ __launch_bounds__(256) void gru_combine(
    const _Float16* __restrict__ gi, const _Float16* __restrict__ gh,
    const float* __restrict__ b_ih, const float* __restrict__ b_hh,
    const float* __restrict__ hprev, float* __restrict__ out, int M)
{
    size_t idx = (size_t)blockIdx.x * 256 + threadIdx.x;
    if (idx >= (size_t)M * NH) return;
    int n = (int)(idx >> 8), j = (int)(idx & (NH - 1));
    size_t b3 = (size_t)n * NH3;
    float ir = (float)gi[b3 + j] + b_ih[j];
    float iz = (float)gi[b3 + NH + j] + b_ih[NH + j];
    float inn = (float)gi[b3 + 2 * NH + j] + b_ih[2 * NH + j];
    float hr = (float)gh[b3 + j] + b_hh[j];
    float hz = (float)gh[b3 + NH + j] + b_hh[NH + j];
    float hn = (float)gh[b3 + 2 * NH + j] + b_hh[2 * NH + j];
    float r = 1.f / (1.f + expf(-(ir + hr)));
    float z = 1.f / (1.f + expf(-(iz + hz)));
    float nn = tanhf(inn + r * hn);
    float hv = (1.f - z) * nn + z * hprev[idx];
    out[idx] = fmaxf(hv, 0.f);
}

extern "C" void kernel_launch(void* const* d_in, const int* in_sizes, int n_in,
                              void* d_out, int out_size, void* d_ws, size_t ws_size,
                              hipStream_t stream)
{
    const float* x          = (const float*)d_in[0];
    const float* edge_attr  = (const float*)d_in[1];
    const float* lin1_w     = (const float*)d_in[2];
    const float* lin1_b     = (const float*)d_in[3];
    const float* gate_att_l = (const float*)d_in[4];
    const float* gate_att_r = (const float*)d_in[5];
    const float* gate_lin1_w= (const float*)d_in[6];
    const float* gate_lin2_w= (const float*)d_in[7];
    const float* gate_bias  = (const float*)d_in[8];
    const float* atom_lin_w = (const float*)d_in[9];
    const float* atom_att_src=(const float*)d_in[10];
    const float* atom_att_dst=(const float*)d_in[11];
    const float* atom_bias  = (const float*)d_in[12];
    const float* gru_w_ih   = (const float*)d_in[13];
    const float* gru_w_hh   = (const float*)d_in[14];
    const float* gru_b_ih   = (const float*)d_in[15];
    const float* gru_b_hh   = (const float*)d_in[16];
    const float* mol_lin_w  = (const float*)d_in[17];
    const float* mol_att_src= (const float*)d_in[18];
    const float* mol_att_dst= (const float*)d_in[19];
    const float* mol_bias   = (const float*)d_in[20];
    const float* mol_gru_w_ih=(const float*)d_in[21];
    const float* mol_gru_w_hh=(const float*)d_in[22];
    const float* mol_gru_b_ih=(const float*)d_in[23];
    const float* mol_gru_b_hh=(const float*)d_in[24];
    const float* lin2_w     = (const float*)d_in[25];
    const float* lin2_b     = (const float*)d_in[26];
    const float* fc_w       = (const float*)d_in[27];
    const float* fc_b       = (const float*)d_in[28];
    const int*   edge_index = (const int*)d_in[29];
    const int*   batch      = (const int*)d_in[30];

    const int N = in_sizes[0] / FNODE;
    const int E = in_sizes[1] / FEDGE;
    const int G = NGRAPH;
    const int* src = edge_index;
    const int* dst = edge_index + E;

    float* w = (float*)d_ws;
    size_t o = 0;
    auto alloc = [&](size_t cnt) { size_t r = o; o += cnt; return r; };
    const size_t o_B1    = alloc((size_t)N * NH);          // x0 -> xcur (in-place GRU)
    const size_t o_B2    = alloc((size_t)N * NH);          // nodepart -> hraw ; mol buffers
    const size_t o_B3    = alloc((size_t)CHUNK * 1024);    // tmp f32(256) + gi f16(768) + gh f16(768)
    const size_t o_elog  = alloc((size_t)E);
    const size_t o_dotr  = alloc((size_t)N);
    const size_t o_adst  = alloc((size_t)N);
    const size_t o_ddot  = alloc((size_t)G);
    const size_t o_vvec  = alloc((size_t)NH);
    const size_t o_usrc  = alloc((size_t)NH);
    const size_t o_udst  = alloc((size_t)NH);
    const size_t o_rowp  = alloc((size_t)N + 1);           // int
    const size_t o_deg   = alloc((size_t)N);               // int
    const size_t o_curs  = alloc((size_t)N);               // int
    const size_t o_esrc  = alloc((size_t)E);               // int
    const size_t o_eidx  = alloc((size_t)E);               // int
    const size_t o_gptr  = alloc((size_t)G + 1);           // int
    if (o * sizeof(float) > ws_size) {
        fprintf(stderr, "kernel_launch: ws too small: need %zu have %zu\n", o * 4, ws_size);
        return;
    }

    float* B1   = w + o_B1;
    float* B2   = w + o_B2;
    float* B3   = w + o_B3;
    float* elog = w + o_elog;
    float* dotr = w + o_dotr;
    float* adst = w + o_adst;
    float* ddot = w + o_ddot;
    float* vvec = w + o_vvec;
    float* usrc = w + o_usrc;
    float* udst = w + o_udst;
    int* rowptr = (int*)(w + o_rowp);
    int* deg    = (int*)(w + o_deg);
    int* cursor = (int*)(w + o_curs);
    int* esrc   = (int*)(w + o_esrc);
    int* eidx   = (int*)(w + o_eidx);
    int* gptr   = (int*)(w + o_gptr);

    // mol-phase sub-buffers inside B2
    float*    gout   = B2;                                             // G*NH f32
    float*    hraw_g = B2 + (size_t)G * NH;                            // G*NH f32
    float*    h_g    = B2 + (size_t)2 * G * NH;                        // G*NH f32
    _Float16* gig    = (_Float16*)(B2 + (size_t)3 * G * NH);           // G*NH3 f16
    _Float16* ghg    = (_Float16*)(B2 + (size_t)3 * G * NH + (size_t)G * NH3 / 2);
    float*    emb    = B2 + (size_t)3 * G * NH + (size_t)G * NH3;      // G*NH f32

    const int BLK = 256;
    auto cdiv = [](size_t a, size_t b) { return (int)((a + b - 1) / b); };
    const int gridEdgeWave = cdiv(E, 4);
    const int gridNodeWave = cdiv(N, 4);
    const int gridEdgeThr = cdiv(E, BLK);
    const int gridNodeThr = cdiv(N, BLK);

    // ---------- CSR build (once) ----------
    zero_i32<<<gridNodeThr, BLK, 0, stream>>>(deg, N);
    hist_dst<<<gridEdgeThr, BLK, 0, stream>>>(dst, deg, E);
    scan_rowptr<<<1, BLK, 0, stream>>>(deg, rowptr, cursor, N);
    csr_scatter<<<gridEdgeThr, BLK, 0, stream>>>(src, dst, cursor, esrc, eidx, E);
    gptr_build<<<cdiv(G + 1, BLK), BLK, 0, stream>>>(batch, gptr, N, G);

    // Per-layer tail: h = elu(hraw@Wh^T + bh) ; GRU(h, xbuf) -> xbuf (chunked, in place)
    auto run_tail = [&](const float* Wh, const float* bh,
                        const float* wih, const float* whh,
                        const float* bih, const float* bhh, float* xbuf) {
        float*    tmp = B3;                                        // CHUNK*NH f32
        _Float16* gi  = (_Float16*)(B3 + (size_t)CHUNK * NH);      // CHUNK*NH3 f16
        _Float16* gh  = (_Float16*)(B3 + (size_t)CHUNK * 640);     // CHUNK*NH3 f16
        for (int c0 = 0; c0 < N; c0 += CHUNK) {
            int mc = (N - c0) < CHUNK ? (N - c0) : CHUNK;
            dim3 gH(4, cdiv(mc, 128));
            dim3 gD(12, cdiv(mc, 128), 2);
            gemm_mfma<2, 0><<<gH, BLK, 0, stream>>>(B2 + (size_t)c0 * NH, Wh, bh, tmp, mc, NH, NH, NH);
            gemm_mfma2<0, 1><<<gD, BLK, 0, stream>>>(tmp, xbuf + (size_t)c0 * NH, wih, whh,
                                                     gi, gh, mc, NH, NH3);
            gru_combine<<<cdiv((size_t)mc * NH, BLK), BLK, 0, stream>>>(
                gi, gh, bih, bhh, xbuf + (size_t)c0 * NH, xbuf + (size_t)c0 * NH, mc);
        }
    };

    dim3 gridNH(4, cdiv(N, 128));

    // ---------- x0 = lrelu(x @ lin1_w^T + lin1_b) ----------
    gemm_mfma<1, 0><<<gridNH, BLK, 0, stream>>>(x, lin1_w, lin1_b, B1, N, FNODE, NH, FNODE);

    // ---------- GATEConv ----------
    gemm_mfma<0, 0><<<gridNH, BLK, 0, stream>>>(B1, gate_lin1_w, nullptr, B2, N, NH, NH, LDW_GATE1);
    node_dot<<<gridNodeWave, BLK, 0, stream>>>(B1, gate_att_r, nullptr, dotr, nullptr, N);
    gate_edge_logit<<<gridEdgeWave, BLK, 0, stream>>>(B2, edge_attr, gate_lin1_w, gate_att_l,
                                                      dotr, src, dst, elog, E);
    gate_agg_csr<<<gridNodeWave, BLK, 0, stream>>>(B1, elog, rowptr, esrc, eidx, B2, N);
    run_tail(gate_lin2_w, gate_bias, gru_w_ih, gru_w_hh, gru_b_ih, gru_b_hh, B1);

    // ---------- 3 GATConv layers ----------
    for (int l = 0; l < 3; ++l) {
        const float* wl = atom_lin_w + (size_t)l * NH * NH;
        matvec_left<<<1, BLK, 0, stream>>>(wl, atom_att_src + l * NH, usrc);
        matvec_left<<<1, BLK, 0, stream>>>(wl, atom_att_dst + l * NH, udst);
        node_dot<<<gridNodeWave, BLK, 0, stream>>>(B1, usrc, udst, dotr, adst, N);
        gat_agg_csr<<<gridNodeWave, BLK, 0, stream>>>(B1, dotr, adst, rowptr, esrc, B2, N);
        run_tail(wl, atom_bias + l * NH,
                 gru_w_ih + (size_t)(l + 1) * NH3 * NH, gru_w_hh + (size_t)(l + 1) * NH3 * NH,
                 gru_b_ih + (size_t)(l + 1) * NH3, gru_b_hh + (size_t)(l + 1) * NH3, B1);
    }

    // ---------- Molecule pooling ----------
    const size_t GHtot = (size_t)G * NH;
    const int gridGWave = cdiv(G, 4);
    graph_sum_relu<<<gridGWave, BLK, 0, stream>>>(B1, gptr, gout, G);
    matvec_left<<<1, BLK, 0, stream>>>(mol_lin_w, mol_att_src, usrc);
    matvec_left<<<1, BLK, 0, stream>>>(mol_lin_w, mol_att_dst, vvec);
    node_dot<<<gridNodeWave, BLK, 0, stream>>>(B1, usrc, nullptr, dotr, nullptr, N);

    dim3 gridGH(4, cdiv(G, 128));
    dim3 gridGD(12, cdiv(G, 128), 2);
    for (int t = 0; t < 2; ++t) {
        node_dot<<<gridGWave, BLK, 0, stream>>>(gout, vvec, nullptr, ddot, nullptr, G);
        mol_agg_csr<<<gridGWave, BLK, 0, stream>>>(B1, dotr, ddot, gptr, hraw_g, G);
        gemm_mfma<2, 0><<<gridGH, BLK, 0, stream>>>(hraw_g, mol_lin_w, mol_bias, h_g, G, NH, NH, NH);
        gemm_mfma2<0, 1><<<gridGD, BLK, 0, stream>>>(h_g, gout, mol_gru_w_ih, mol_gru_w_hh,
                                                     gig, ghg, G, NH, NH3);
        gru_combine<<<cdiv(GHtot, BLK), BLK, 0, stream>>>(gig, ghg, mol_gru_b_ih, mol_gru_b_hh,
                                                          gout, gout, G);
    }

    // ---------- readout ----------
    gemm_mfma<0, 0><<<gridGH, BLK, 0, stream>>>(gout, lin2_w, lin2_b, emb, G, NH, NH, NH);
    dim3 gridFc(1, cdiv(G, 64));
    gemm_nt<<<gridFc, BLK, 0, stream>>>(emb, fc_w, fc_b, (float*)d_out, G, NH, NTASK, NH, 0);
}